// Round 1
// baseline (197.571 us; speedup 1.0000x reference)
//
#include <hip/hip_runtime.h>
#include <hip/hip_bf16.h>

typedef __attribute__((ext_vector_type(8))) short short8;   // 8 x bf16 (4 VGPR)
typedef __attribute__((ext_vector_type(4))) float f32x4;

static __device__ __forceinline__ unsigned short f2bf(float f) {
    union { float f; unsigned u; } v; v.f = f;
    unsigned r = v.u + 0x7fffu + ((v.u >> 16) & 1u);   // round-to-nearest-even
    return (unsigned short)(r >> 16);
}

// ---------------------------------------------------------------------------
// Kernel 1: QKV projection.  x:[16384,256] f32  ->  Qb,Kb bf16 [16384][32],
// Vt bf16 [4][256][4096] (transposed so PV B-fragments are contiguous).
// Grid: 256 blocks x 256 thr.  Per block: 64-token M-tile, all 320 out cols.
// ---------------------------------------------------------------------------
__global__ __launch_bounds__(256) void proj_kernel(
    const float* __restrict__ x,
    const float* __restrict__ Wq, const float* __restrict__ bq,
    const float* __restrict__ Wk, const float* __restrict__ bk,
    const float* __restrict__ Wv, const float* __restrict__ bv,
    unsigned short* __restrict__ Qb, unsigned short* __restrict__ Kb,
    unsigned short* __restrict__ Vt)
{
    __shared__ unsigned short x_lds[64][264];   // pad 8 -> 528B row stride (conflict-free b128)
    const int tid = threadIdx.x;
    const int M0  = blockIdx.x * 64;            // global token base (tile never straddles batch)

    // stage x tile (64x256 f32) -> bf16 LDS, coalesced float4 loads
    #pragma unroll
    for (int j = 0; j < 16; ++j) {
        int idx = j * 256 + tid;                // quad index
        int row = idx >> 6;
        int qc  = idx & 63;
        const float4 v = *reinterpret_cast<const float4*>(x + (size_t)(M0 + row) * 256 + qc * 4);
        ushort4 o;
        o.x = f2bf(v.x); o.y = f2bf(v.y); o.z = f2bf(v.z); o.w = f2bf(v.w);
        *reinterpret_cast<ushort4*>(&x_lds[row][qc * 4]) = o;
    }
    __syncthreads();

    const int w  = tid >> 6;
    const int l  = tid & 63;
    const int lr = l & 15;
    const int lg = l >> 4;

    // A fragments: wave w owns rows w*16 .. w*16+15
    short8 a[8];
    #pragma unroll
    for (int kk = 0; kk < 8; ++kk)
        a[kk] = *reinterpret_cast<const short8*>(&x_lds[w * 16 + lr][kk * 32 + lg * 8]);

    for (int ct = 0; ct < 20; ++ct) {
        const float* Wsel; const float* bsel; int ldw, colp;
        int col = ct * 16 + lr;
        if (ct < 2)      { Wsel = Wq; bsel = bq; ldw = 32;  colp = col; }
        else if (ct < 4) { Wsel = Wk; bsel = bk; ldw = 32;  colp = col - 32; }
        else             { Wsel = Wv; bsel = bv; ldw = 256; colp = col - 64; }

        f32x4 acc = {0.f, 0.f, 0.f, 0.f};
        #pragma unroll
        for (int kk = 0; kk < 8; ++kk) {
            short8 bfr;
            const float* wp = Wsel + (size_t)(kk * 32 + lg * 8) * ldw + colp;
            #pragma unroll
            for (int j = 0; j < 8; ++j) bfr[j] = (short)f2bf(wp[j * ldw]);
            acc = __builtin_amdgcn_mfma_f32_16x16x32_bf16(a[kk], bfr, acc, 0, 0, 0);
        }

        const float bias = bsel[colp];
        const int rbase = M0 + w * 16 + lg * 4;     // global token of reg 0
        if (ct < 4) {
            unsigned short* dst = (ct < 2) ? Qb : Kb;
            #pragma unroll
            for (int r = 0; r < 4; ++r)
                dst[(size_t)(rbase + r) * 32 + colp] = f2bf(acc[r] + bias);
        } else {
            const int b  = M0 >> 12;
            const int n0 = rbase & 4095;
            ushort4 o;
            o.x = f2bf(acc[0] + bias); o.y = f2bf(acc[1] + bias);
            o.z = f2bf(acc[2] + bias); o.w = f2bf(acc[3] + bias);
            *reinterpret_cast<ushort4*>(Vt + ((size_t)b * 256 + colp) * 4096 + n0) = o;
        }
    }
}

// ---------------------------------------------------------------------------
// Kernel 2: flash attention + epilogue  out = gamma * softmax(QK^T) V + x
// Grid 256 wgs (XCD-swizzled: batch b -> XCD pair {2b,2b+1}), 4 waves.
// Wave w: softmax-owner of q-rows [w*16,w*16+16); PV-computer of cols [w*64,w*64+64).
// ---------------------------------------------------------------------------
__global__ __launch_bounds__(256) void attn_kernel(
    const unsigned short* __restrict__ Qb, const unsigned short* __restrict__ Kb,
    const unsigned short* __restrict__ Vt, const float* __restrict__ x,
    const float* __restrict__ gamma_p, float* __restrict__ out)
{
    __shared__ unsigned short P_lds[64][72];   // pad 8 -> 144B stride, conflict-free b128
    __shared__ float sc_lds[64];
    __shared__ float l_lds[64];

    const int i  = blockIdx.x;
    const int b  = (i & 7) >> 1;                     // batch -> XCD pair
    const int mt = ((i >> 3) << 1) | (i & 1);        // q-tile 0..63 (bijective)

    const int tid = threadIdx.x;
    const int w   = tid >> 6;
    const int l   = tid & 63;
    const int lr  = l & 15;
    const int lg  = l >> 4;

    const size_t bN  = (size_t)b * 4096;
    const unsigned short* Kbb = Kb + bN * 32;
    const unsigned short* Vtb = Vt + (size_t)b * 256 * 4096;

    // Q fragment: owner rows mt*64 + w*16 + lr, full d=32 (one A-frag)
    const short8 qf = *reinterpret_cast<const short8*>(
        Qb + (bN + (size_t)mt * 64 + w * 16 + lr) * 32 + lg * 8);

    float m_run[4] = {-1e30f, -1e30f, -1e30f, -1e30f};
    float l_run[4] = {0.f, 0.f, 0.f, 0.f};
    f32x4 Oa[4][4];                                   // [m-tile][col-tile]
    #pragma unroll
    for (int m = 0; m < 4; ++m)
        #pragma unroll
        for (int ct = 0; ct < 4; ++ct) Oa[m][ct] = (f32x4){0.f, 0.f, 0.f, 0.f};

    const f32x4 zero = {0.f, 0.f, 0.f, 0.f};

    for (int kt = 0; kt < 64; ++kt) {
        // ---- owner: S = Q K^T for 16 rows x 64 cols (4 MFMA) ----
        f32x4 s[4];
        #pragma unroll
        for (int t = 0; t < 4; ++t) {
            const short8 kf = *reinterpret_cast<const short8*>(
                Kbb + (size_t)(kt * 64 + t * 16 + lr) * 32 + lg * 8);
            s[t] = __builtin_amdgcn_mfma_f32_16x16x32_bf16(qf, kf, zero, 0, 0, 0);
        }
        // ---- online softmax (row r = lg*4 + reg; reduce over 16 lanes of group) ----
        float sc[4];
        unsigned short p16[4][4];
        #pragma unroll
        for (int r = 0; r < 4; ++r) {
            float m = fmaxf(fmaxf(s[0][r], s[1][r]), fmaxf(s[2][r], s[3][r]));
            m = fmaxf(m, __shfl_xor(m, 1));
            m = fmaxf(m, __shfl_xor(m, 2));
            m = fmaxf(m, __shfl_xor(m, 4));
            m = fmaxf(m, __shfl_xor(m, 8));
            const float mn = fmaxf(m_run[r], m);
            sc[r] = __expf(m_run[r] - mn);
            m_run[r] = mn;
            float sum = 0.f;
            #pragma unroll
            for (int t = 0; t < 4; ++t) {
                const float p = __expf(s[t][r] - mn);
                sum += p;
                p16[t][r] = f2bf(p);
            }
            sum += __shfl_xor(sum, 1);
            sum += __shfl_xor(sum, 2);
            sum += __shfl_xor(sum, 4);
            sum += __shfl_xor(sum, 8);
            l_run[r] = l_run[r] * sc[r] + sum;
        }
        // publish P (bf16) + rescale factors
        #pragma unroll
        for (int t = 0; t < 4; ++t)
            #pragma unroll
            for (int r = 0; r < 4; ++r)
                P_lds[w * 16 + lg * 4 + r][t * 16 + lr] = p16[t][r];
        if (lr == 0) {
            #pragma unroll
            for (int r = 0; r < 4; ++r) sc_lds[w * 16 + lg * 4 + r] = sc[r];
        }
        __syncthreads();

        // ---- computer: rescale O, then O += P V for cols w*64.. ----
        #pragma unroll
        for (int m = 0; m < 4; ++m) {
            float scm[4];
            #pragma unroll
            for (int r = 0; r < 4; ++r) scm[r] = sc_lds[m * 16 + lg * 4 + r];
            #pragma unroll
            for (int ct = 0; ct < 4; ++ct)
                #pragma unroll
                for (int r = 0; r < 4; ++r) Oa[m][ct][r] *= scm[r];
        }
        short8 pa[4][2];
        #pragma unroll
        for (int m = 0; m < 4; ++m)
            #pragma unroll
            for (int kc = 0; kc < 2; ++kc)
                pa[m][kc] = *reinterpret_cast<const short8*>(
                    &P_lds[m * 16 + lr][kc * 32 + lg * 8]);
        #pragma unroll
        for (int ct = 0; ct < 4; ++ct) {
            const int col = w * 64 + ct * 16 + lr;
            #pragma unroll
            for (int kc = 0; kc < 2; ++kc) {
                const short8 vf = *reinterpret_cast<const short8*>(
                    Vtb + (size_t)col * 4096 + kt * 64 + kc * 32 + lg * 8);
                #pragma unroll
                for (int m = 0; m < 4; ++m)
                    Oa[m][ct] = __builtin_amdgcn_mfma_f32_16x16x32_bf16(pa[m][kc], vf, Oa[m][ct], 0, 0, 0);
            }
        }
        __syncthreads();   // protect P_lds/sc_lds before next iteration's writes
    }

    // ---- finalize: publish row sums, normalize, epilogue ----
    if (lr == 0) {
        #pragma unroll
        for (int r = 0; r < 4; ++r) l_lds[w * 16 + lg * 4 + r] = l_run[r];
    }
    __syncthreads();

    const float gamma = gamma_p[0];
    #pragma unroll
    for (int m = 0; m < 4; ++m) {
        float linv[4];
        #pragma unroll
        for (int r = 0; r < 4; ++r) linv[r] = 1.f / l_lds[m * 16 + lg * 4 + r];
        #pragma unroll
        for (int ct = 0; ct < 4; ++ct) {
            const int col = w * 64 + ct * 16 + lr;
            #pragma unroll
            for (int r = 0; r < 4; ++r) {
                const int row = mt * 64 + m * 16 + lg * 4 + r;
                const size_t idx = (bN + row) * 256 + col;
                out[idx] = gamma * (Oa[m][ct][r] * linv[r]) + x[idx];
            }
        }
    }
}

// ---------------------------------------------------------------------------
extern "C" void kernel_launch(void* const* d_in, const int* in_sizes, int n_in,
                              void* d_out, int out_size, void* d_ws, size_t ws_size,
                              hipStream_t stream) {
    const float* x     = (const float*)d_in[0];
    const float* Wq    = (const float*)d_in[1];
    const float* bq    = (const float*)d_in[2];
    const float* Wk    = (const float*)d_in[3];
    const float* bk    = (const float*)d_in[4];
    const float* Wv    = (const float*)d_in[5];
    const float* bv    = (const float*)d_in[6];
    const float* gamma = (const float*)d_in[7];
    float* out = (float*)d_out;

    // workspace: Qb 1MB | Kb 1MB | Vt 8MB  (bf16)  -> 10.5 MB total
    unsigned short* Qb = (unsigned short*)d_ws;
    unsigned short* Kb = Qb + (size_t)16384 * 32;
    unsigned short* Vt = Kb + (size_t)16384 * 32;

    proj_kernel<<<256, 256, 0, stream>>>(x, Wq, bq, Wk, bk, Wv, bv, Qb, Kb, Vt);
    attn_kernel<<<256, 256, 0, stream>>>(Qb, Kb, Vt, x, gamma, out);
}